// Round 4
// baseline (851.989 us; speedup 1.0000x reference)
//
#include <hip/hip_runtime.h>
#include <math.h>

#define NNODE 2048
#define NEDGE 32768
#define HID   128
#define KIN   260          // 2*H + 4 edge feats
#define NMAT  (NNODE * NNODE)
#define EB    64           // edges per block in msg kernel

// ---------------------------------------------------------------------------
// init: adj_idx = -1, degree histograms = 0
// ---------------------------------------------------------------------------
__global__ __launch_bounds__(256) void init_kernel(int* __restrict__ adj_idx,
                                                   int* __restrict__ deg_src,
                                                   int* __restrict__ deg_dst) {
    int gid = blockIdx.x * 256 + threadIdx.x;
    int stride = gridDim.x * 256;
    for (int i = gid; i < NMAT; i += stride) adj_idx[i] = -1;
    if (gid < NNODE) { deg_src[gid] = 0; deg_dst[gid] = 0; }
}

// ---------------------------------------------------------------------------
// scatter+hist: last-edge-index-wins dedup matrix + degree histograms
// ---------------------------------------------------------------------------
__global__ __launch_bounds__(256) void scatter_kernel(const int* __restrict__ ei,
                                                      int* __restrict__ adj_idx,
                                                      int* __restrict__ deg_src,
                                                      int* __restrict__ deg_dst) {
    int e = blockIdx.x * 256 + threadIdx.x;
    if (e < NEDGE) {
        int s = ei[e];
        int d = ei[NEDGE + e];
        atomicMax(&adj_idx[(size_t)s * NNODE + d], e);
        atomicAdd(&deg_src[s], 1);
        atomicAdd(&deg_dst[d], 1);
    }
}

// ---------------------------------------------------------------------------
// exclusive scan of both degree arrays (2048 each), single block
// ---------------------------------------------------------------------------
__global__ __launch_bounds__(256) void scan_kernel(const int* __restrict__ deg_src,
                                                   const int* __restrict__ deg_dst,
                                                   int* __restrict__ off_src,
                                                   int* __restrict__ off_dst,
                                                   int* __restrict__ cur_src,
                                                   int* __restrict__ cur_dst) {
    __shared__ int part[256];
    int t = threadIdx.x;
    for (int which = 0; which < 2; ++which) {
        const int* deg = which ? deg_dst : deg_src;
        int* off = which ? off_dst : off_src;
        int* cur = which ? cur_dst : cur_src;
        __syncthreads();
        int base = t * 8;
        int local[8];
        int s = 0;
        #pragma unroll
        for (int i = 0; i < 8; ++i) { local[i] = deg[base + i]; s += local[i]; }
        part[t] = s;
        __syncthreads();
        if (t == 0) {
            int run = 0;
            for (int i = 0; i < 256; ++i) { int v = part[i]; part[i] = run; run += v; }
        }
        __syncthreads();
        int run = part[t];
        #pragma unroll
        for (int i = 0; i < 8; ++i) {
            off[base + i] = run;
            cur[base + i] = run;
            run += local[i];
        }
        if (t == 255) off[NNODE] = run;
    }
}

// ---------------------------------------------------------------------------
// fill CSR edge lists (order within bucket arbitrary — sums only)
// ---------------------------------------------------------------------------
__global__ __launch_bounds__(256) void fill_kernel(const int* __restrict__ ei,
                                                   int* __restrict__ cur_src,
                                                   int* __restrict__ cur_dst,
                                                   int* __restrict__ list_src,
                                                   int* __restrict__ list_dst) {
    int e = blockIdx.x * 256 + threadIdx.x;
    if (e < NEDGE) {
        int s = ei[e];
        int d = ei[NEDGE + e];
        int p1 = atomicAdd(&cur_src[s], 1);
        list_src[p1] = e;
        int p2 = atomicAdd(&cur_dst[d], 1);
        list_dst[p2] = e;
    }
}

// ---------------------------------------------------------------------------
// sparse residuals: wave per edge (A,C); lanes walk out-neighbors of A,
// dedup via winner check, probe adj_idx[B][C]. Writes res and w = exp(-res).
// ---------------------------------------------------------------------------
__global__ __launch_bounds__(256) void residual_kernel(const int* __restrict__ ei,
                                                       const float* __restrict__ dist,
                                                       const int* __restrict__ adj_idx,
                                                       const int* __restrict__ off_src,
                                                       const int* __restrict__ list_src,
                                                       float* __restrict__ res_out,
                                                       float* __restrict__ wbuf) {
    int wv = threadIdx.x >> 6;
    int lane = threadIdx.x & 63;
    int e = blockIdx.x * 4 + wv;
    int A = ei[e];
    int C = ei[NEDGE + e];
    int beg = off_src[A];
    int end = off_src[A + 1];
    float sum = 0.0f, cnt = 0.0f;
    for (int i = beg + lane; i < end; i += 64) {
        int ep = list_src[i];
        int B = ei[NEDGE + ep];
        if (adj_idx[(size_t)A * NNODE + B] == ep) {      // ep is the winner of (A,B)
            int idx2 = adj_idx[(size_t)B * NNODE + C];
            if (idx2 >= 0) { sum += dist[ep] + dist[idx2]; cnt += 1.0f; }
        }
    }
    #pragma unroll
    for (int off = 32; off > 0; off >>= 1) {
        sum += __shfl_down(sum, off, 64);
        cnt += __shfl_down(cnt, off, 64);
    }
    if (lane == 0) {
        float d = dist[e];
        float mean = (cnt > 0.0f) ? (sum / cnt) : d;
        float r = fabsf(d - mean);
        res_out[e] = r;
        wbuf[e] = expf(-r);
    }
}

// ---------------------------------------------------------------------------
// message MLP v2: 64 edges/block, 256 threads.
// eg = tid&15 -> 4 edges each; jg = tid>>4 -> 8 outputs each; acc[4][8].
// Per kk: 2 conflict-free b128 weight broadcasts + 4 two-way-free b32 x reads
// -> 32 FMAs. Writes RAW messages (no atomics).
// ---------------------------------------------------------------------------
__global__ __launch_bounds__(256) void msg_kernel(const float* __restrict__ mu,
                                                  const float* __restrict__ sigma,
                                                  const int* __restrict__ ei,
                                                  const float* __restrict__ dist,
                                                  const float* __restrict__ conf,
                                                  const float* __restrict__ angle,
                                                  const float* __restrict__ ddiff,
                                                  const float* __restrict__ w1,
                                                  const float* __restrict__ b1,
                                                  const float* __restrict__ w2,
                                                  const float* __restrict__ b2,
                                                  float* __restrict__ wmsg) {
    __shared__ float xs[EB][35];       // k-tile 32 + pad (35 % 32 == 3)  ~9 KB
    __shared__ float wt[32 * HID];     // 16 KB
    __shared__ float hs[EB][131];      // 131 % 32 == 3                  ~33.5 KB
    __shared__ int   sid[EB];
    int tid = threadIdx.x;
    int e0 = blockIdx.x * EB;
    int eg = tid & 15;
    int jg = tid >> 4;
    int j0 = jg * 8;
    if (tid < EB) sid[tid] = ei[e0 + tid];
    __syncthreads();

    float acc[4][8];
    #pragma unroll
    for (int q = 0; q < 4; ++q)
        #pragma unroll
        for (int r = 0; r < 8; ++r) acc[q][r] = b1[j0 + r];

    // ---- layer 1: KIN = 260 = 8*32 + 4 ----
    for (int t = 0; t < 9; ++t) {
        int k0 = t * 32;
        int rows = (t == 8) ? 4 : 32;
        __syncthreads();
        // stage x tile (gather)
        if (t < 8) {
            const float* basep = (t < 4) ? mu : sigma;
            int kbase = (t < 4) ? k0 : (k0 - HID);
            #pragma unroll
            for (int p = 0; p < 4; ++p) {
                int e = p * 16 + jg;
                int k2 = eg * 2;
                const float* row = basep + (size_t)sid[e] * HID + kbase;
                float2 v = *(const float2*)(row + k2);
                xs[e][k2] = v.x;
                xs[e][k2 + 1] = v.y;
            }
        } else {
            if (tid < EB) {
                int ge = e0 + tid;
                xs[tid][0] = dist[ge];
                xs[tid][1] = conf[ge];
                xs[tid][2] = angle[ge];
                xs[tid][3] = ddiff[ge];
            }
        }
        // stage weight tile
        {
            const float4* src = (const float4*)(w1 + (size_t)k0 * HID);
            int n4 = rows * (HID / 4);
            for (int i = tid; i < n4; i += 256) ((float4*)wt)[i] = src[i];
        }
        __syncthreads();
        for (int kk = 0; kk < rows; ++kk) {
            float4 wa = *(const float4*)&wt[kk * HID + j0];
            float4 wb = *(const float4*)&wt[kk * HID + j0 + 4];
            #pragma unroll
            for (int q = 0; q < 4; ++q) {
                float xv = xs[4 * eg + q][kk];
                acc[q][0] = fmaf(xv, wa.x, acc[q][0]);
                acc[q][1] = fmaf(xv, wa.y, acc[q][1]);
                acc[q][2] = fmaf(xv, wa.z, acc[q][2]);
                acc[q][3] = fmaf(xv, wa.w, acc[q][3]);
                acc[q][4] = fmaf(xv, wb.x, acc[q][4]);
                acc[q][5] = fmaf(xv, wb.y, acc[q][5]);
                acc[q][6] = fmaf(xv, wb.z, acc[q][6]);
                acc[q][7] = fmaf(xv, wb.w, acc[q][7]);
            }
        }
    }
    // relu -> hs
    #pragma unroll
    for (int q = 0; q < 4; ++q)
        #pragma unroll
        for (int r = 0; r < 8; ++r) hs[4 * eg + q][j0 + r] = fmaxf(acc[q][r], 0.0f);

    // ---- layer 2: 128 = 4*32 ----
    #pragma unroll
    for (int q = 0; q < 4; ++q)
        #pragma unroll
        for (int r = 0; r < 8; ++r) acc[q][r] = b2[j0 + r];
    for (int t = 0; t < 4; ++t) {
        int k0 = t * 32;
        __syncthreads();
        {
            const float4* src = (const float4*)(w2 + (size_t)k0 * HID);
            for (int i = tid; i < 32 * (HID / 4); i += 256) ((float4*)wt)[i] = src[i];
        }
        __syncthreads();
        for (int kk = 0; kk < 32; ++kk) {
            float4 wa = *(const float4*)&wt[kk * HID + j0];
            float4 wb = *(const float4*)&wt[kk * HID + j0 + 4];
            #pragma unroll
            for (int q = 0; q < 4; ++q) {
                float xv = hs[4 * eg + q][k0 + kk];
                acc[q][0] = fmaf(xv, wa.x, acc[q][0]);
                acc[q][1] = fmaf(xv, wa.y, acc[q][1]);
                acc[q][2] = fmaf(xv, wa.z, acc[q][2]);
                acc[q][3] = fmaf(xv, wa.w, acc[q][3]);
                acc[q][4] = fmaf(xv, wb.x, acc[q][4]);
                acc[q][5] = fmaf(xv, wb.y, acc[q][5]);
                acc[q][6] = fmaf(xv, wb.z, acc[q][6]);
                acc[q][7] = fmaf(xv, wb.w, acc[q][7]);
            }
        }
    }
    // store raw messages
    #pragma unroll
    for (int q = 0; q < 4; ++q) {
        float* orow = wmsg + (size_t)(e0 + 4 * eg + q) * HID + j0;
        float4 v0 = make_float4(acc[q][0], acc[q][1], acc[q][2], acc[q][3]);
        float4 v1 = make_float4(acc[q][4], acc[q][5], acc[q][6], acc[q][7]);
        *(float4*)orow = v0;
        *(float4*)(orow + 4) = v1;
    }
}

// ---------------------------------------------------------------------------
// gather: per node, sum weighted incoming messages via dst-CSR (coalesced),
// normalize, and compute mean incoming residual. No atomics.
// ---------------------------------------------------------------------------
__global__ __launch_bounds__(128) void gather_kernel(const float* __restrict__ wmsg,
                                                     const float* __restrict__ wbuf,
                                                     const float* __restrict__ res,
                                                     const int* __restrict__ off_dst,
                                                     const int* __restrict__ list_dst,
                                                     float* __restrict__ aggn,
                                                     float* __restrict__ mean_r) {
    int n = blockIdx.x;
    int j = threadIdx.x;
    int beg = off_dst[n];
    int end = off_dst[n + 1];
    float acc = 0.0f, ws = 0.0f, rs = 0.0f;
    for (int i = beg; i < end; ++i) {
        int e = list_dst[i];
        float w = wbuf[e];
        acc += w * wmsg[(size_t)e * HID + j];
        ws += w;
        rs += res[e];
    }
    aggn[(size_t)n * HID + j] = acc / fmaxf(ws, 1e-8f);
    if (j == 0) {
        float c = (float)(end - beg);
        mean_r[n] = rs / fmaxf(c, 1.0f);
    }
}

// ---------------------------------------------------------------------------
// node mu MLP: mu_new = mu + mlp(aggn)
// ---------------------------------------------------------------------------
__global__ __launch_bounds__(256) void mu_kernel(const float* __restrict__ mu,
                                                 const float* __restrict__ aggn,
                                                 const float* __restrict__ w1,
                                                 const float* __restrict__ b1,
                                                 const float* __restrict__ w2,
                                                 const float* __restrict__ b2,
                                                 float* __restrict__ out) {
    __shared__ float xs[16][132];
    __shared__ float wt[32 * HID];
    __shared__ float hs[16][132];
    int tid = threadIdx.x;
    int n0 = blockIdx.x * 16;
    {
        int nl = tid >> 4, l = tid & 15;
        int n = n0 + nl;
        for (int k = l; k < HID; k += 16)
            xs[nl][k] = aggn[(size_t)n * HID + k];
    }
    __syncthreads();
    int nl = tid >> 4, jg = tid & 15, j0 = jg * 8;
    float acc[8];
    #pragma unroll
    for (int r = 0; r < 8; ++r) acc[r] = b1[j0 + r];
    for (int k0 = 0; k0 < HID; k0 += 32) {
        __syncthreads();
        for (int i = tid; i < 32 * (HID / 4); i += 256)
            ((float4*)wt)[i] = ((const float4*)(w1 + (size_t)k0 * HID))[i];
        __syncthreads();
        for (int kk = 0; kk < 32; ++kk) {
            float xv = xs[nl][k0 + kk];
            const float* wr = wt + kk * HID + j0;
            #pragma unroll
            for (int r = 0; r < 8; ++r) acc[r] = fmaf(xv, wr[r], acc[r]);
        }
    }
    #pragma unroll
    for (int r = 0; r < 8; ++r) hs[nl][j0 + r] = fmaxf(acc[r], 0.0f);
    #pragma unroll
    for (int r = 0; r < 8; ++r) acc[r] = b2[j0 + r];
    for (int k0 = 0; k0 < HID; k0 += 32) {
        __syncthreads();
        for (int i = tid; i < 32 * (HID / 4); i += 256)
            ((float4*)wt)[i] = ((const float4*)(w2 + (size_t)k0 * HID))[i];
        __syncthreads();
        for (int kk = 0; kk < 32; ++kk) {
            float xv = hs[nl][k0 + kk];
            const float* wr = wt + kk * HID + j0;
            #pragma unroll
            for (int r = 0; r < 8; ++r) acc[r] = fmaf(xv, wr[r], acc[r]);
        }
    }
    int n = n0 + nl;
    #pragma unroll
    for (int r = 0; r < 8; ++r)
        out[(size_t)n * HID + j0 + r] = mu[(size_t)n * HID + j0 + r] + acc[r];
}

// ---------------------------------------------------------------------------
// node sigma MLP: sigma_new = softplus(mlp([aggn, mean_r]))  (K = 129)
// ---------------------------------------------------------------------------
__global__ __launch_bounds__(256) void sig_kernel(const float* __restrict__ aggn,
                                                  const float* __restrict__ mean_r,
                                                  const float* __restrict__ w1,
                                                  const float* __restrict__ b1,
                                                  const float* __restrict__ w2,
                                                  const float* __restrict__ b2,
                                                  float* __restrict__ out) {
    __shared__ float xs[16][132];
    __shared__ float wt[32 * HID];
    __shared__ float hs[16][132];
    int tid = threadIdx.x;
    int n0 = blockIdx.x * 16;
    {
        int nl = tid >> 4, l = tid & 15;
        int n = n0 + nl;
        for (int k = l; k < HID; k += 16)
            xs[nl][k] = aggn[(size_t)n * HID + k];
        if (l == 0)
            xs[nl][HID] = mean_r[n];
    }
    __syncthreads();
    int nl = tid >> 4, jg = tid & 15, j0 = jg * 8;
    float acc[8];
    #pragma unroll
    for (int r = 0; r < 8; ++r) acc[r] = b1[j0 + r];
    for (int k0 = 0; k0 < 129; k0 += 32) {
        int rows = (129 - k0 < 32) ? (129 - k0) : 32;
        __syncthreads();
        for (int i = tid; i < rows * (HID / 4); i += 256)
            ((float4*)wt)[i] = ((const float4*)(w1 + (size_t)k0 * HID))[i];
        __syncthreads();
        for (int kk = 0; kk < rows; ++kk) {
            float xv = xs[nl][k0 + kk];
            const float* wr = wt + kk * HID + j0;
            #pragma unroll
            for (int r = 0; r < 8; ++r) acc[r] = fmaf(xv, wr[r], acc[r]);
        }
    }
    #pragma unroll
    for (int r = 0; r < 8; ++r) hs[nl][j0 + r] = fmaxf(acc[r], 0.0f);
    #pragma unroll
    for (int r = 0; r < 8; ++r) acc[r] = b2[j0 + r];
    for (int k0 = 0; k0 < HID; k0 += 32) {
        __syncthreads();
        for (int i = tid; i < 32 * (HID / 4); i += 256)
            ((float4*)wt)[i] = ((const float4*)(w2 + (size_t)k0 * HID))[i];
        __syncthreads();
        for (int kk = 0; kk < 32; ++kk) {
            float xv = hs[nl][k0 + kk];
            const float* wr = wt + kk * HID + j0;
            #pragma unroll
            for (int r = 0; r < 8; ++r) acc[r] = fmaf(xv, wr[r], acc[r]);
        }
    }
    int n = n0 + nl;
    #pragma unroll
    for (int r = 0; r < 8; ++r) {
        float x = acc[r];
        out[(size_t)n * HID + j0 + r] = fmaxf(x, 0.0f) + log1pf(expf(-fabsf(x)));
    }
}

// ---------------------------------------------------------------------------
extern "C" void kernel_launch(void* const* d_in, const int* in_sizes, int n_in,
                              void* d_out, int out_size, void* d_ws, size_t ws_size,
                              hipStream_t stream) {
    const float* mu     = (const float*)d_in[0];
    const float* sigma  = (const float*)d_in[1];
    const int*   ei     = (const int*)d_in[2];
    const float* dist   = (const float*)d_in[3];
    const float* conf   = (const float*)d_in[4];
    const float* angle  = (const float*)d_in[5];
    const float* ddiff  = (const float*)d_in[6];
    const float* msg_w1 = (const float*)d_in[7];
    const float* msg_b1 = (const float*)d_in[8];
    const float* msg_w2 = (const float*)d_in[9];
    const float* msg_b2 = (const float*)d_in[10];
    const float* mu_w1  = (const float*)d_in[11];
    const float* mu_b1  = (const float*)d_in[12];
    const float* mu_w2  = (const float*)d_in[13];
    const float* mu_b2  = (const float*)d_in[14];
    const float* sig_w1 = (const float*)d_in[15];
    const float* sig_b1 = (const float*)d_in[16];
    const float* sig_w2 = (const float*)d_in[17];
    const float* sig_b2 = (const float*)d_in[18];

    float* out_mu  = (float*)d_out;
    float* out_sig = out_mu + (size_t)NNODE * HID;
    float* out_res = out_sig + (size_t)NNODE * HID;

    char* ws = (char*)d_ws;
    size_t o = 0;
    int*   adj_idx  = (int*)(ws + o);   o += (size_t)NMAT * 4;           // 16.78 MB
    float* wmsg     = (float*)(ws + o); o += (size_t)NEDGE * HID * 4;    // 16.78 MB
    float* wbuf     = (float*)(ws + o); o += (size_t)NEDGE * 4;
    float* aggn     = (float*)(ws + o); o += (size_t)NNODE * HID * 4;
    float* mean_r   = (float*)(ws + o); o += (size_t)NNODE * 4;
    int*   deg_src  = (int*)(ws + o);   o += (size_t)NNODE * 4;
    int*   deg_dst  = (int*)(ws + o);   o += (size_t)NNODE * 4;
    int*   off_src  = (int*)(ws + o);   o += (size_t)(NNODE + 1) * 4;
    int*   off_dst  = (int*)(ws + o);   o += (size_t)(NNODE + 1) * 4;
    int*   cur_src  = (int*)(ws + o);   o += (size_t)NNODE * 4;
    int*   cur_dst  = (int*)(ws + o);   o += (size_t)NNODE * 4;
    int*   list_src = (int*)(ws + o);   o += (size_t)NEDGE * 4;
    int*   list_dst = (int*)(ws + o);   o += (size_t)NEDGE * 4;

    hipLaunchKernelGGL(init_kernel, dim3(4096), dim3(256), 0, stream,
                       adj_idx, deg_src, deg_dst);
    hipLaunchKernelGGL(scatter_kernel, dim3(NEDGE / 256), dim3(256), 0, stream,
                       ei, adj_idx, deg_src, deg_dst);
    hipLaunchKernelGGL(scan_kernel, dim3(1), dim3(256), 0, stream,
                       deg_src, deg_dst, off_src, off_dst, cur_src, cur_dst);
    hipLaunchKernelGGL(fill_kernel, dim3(NEDGE / 256), dim3(256), 0, stream,
                       ei, cur_src, cur_dst, list_src, list_dst);
    hipLaunchKernelGGL(residual_kernel, dim3(NEDGE / 4), dim3(256), 0, stream,
                       ei, dist, adj_idx, off_src, list_src, out_res, wbuf);
    hipLaunchKernelGGL(msg_kernel, dim3(NEDGE / EB), dim3(256), 0, stream,
                       mu, sigma, ei, dist, conf, angle, ddiff,
                       msg_w1, msg_b1, msg_w2, msg_b2, wmsg);
    hipLaunchKernelGGL(gather_kernel, dim3(NNODE), dim3(128), 0, stream,
                       wmsg, wbuf, out_res, off_dst, list_dst, aggn, mean_r);
    hipLaunchKernelGGL(mu_kernel, dim3(NNODE / 16), dim3(256), 0, stream,
                       mu, aggn, mu_w1, mu_b1, mu_w2, mu_b2, out_mu);
    hipLaunchKernelGGL(sig_kernel, dim3(NNODE / 16), dim3(256), 0, stream,
                       aggn, mean_r, sig_w1, sig_b1, sig_w2, sig_b2, out_sig);
}

// Round 5
// 241.631 us; speedup vs baseline: 3.5260x; 3.5260x over previous
//
#include <hip/hip_runtime.h>
#include <math.h>

#define NNODE 2048
#define NEDGE 32768
#define HID   128
#define KIN   260          // 2*H + 4 edge feats
#define NMAT  (NNODE * NNODE)
#define EB    32           // edges per block in msg kernel

// ---------------------------------------------------------------------------
// init: adj_idx = -1, degree histograms = 0
// ---------------------------------------------------------------------------
__global__ __launch_bounds__(256) void init_kernel(int* __restrict__ adj_idx,
                                                   int* __restrict__ deg_src,
                                                   int* __restrict__ deg_dst) {
    int gid = blockIdx.x * 256 + threadIdx.x;
    int stride = gridDim.x * 256;
    for (int i = gid; i < NMAT; i += stride) adj_idx[i] = -1;
    if (gid < NNODE) { deg_src[gid] = 0; deg_dst[gid] = 0; }
}

// ---------------------------------------------------------------------------
// scatter+hist: last-edge-index-wins dedup matrix + degree histograms
// ---------------------------------------------------------------------------
__global__ __launch_bounds__(256) void scatter_kernel(const int* __restrict__ ei,
                                                      int* __restrict__ adj_idx,
                                                      int* __restrict__ deg_src,
                                                      int* __restrict__ deg_dst) {
    int e = blockIdx.x * 256 + threadIdx.x;
    if (e < NEDGE) {
        int s = ei[e];
        int d = ei[NEDGE + e];
        atomicMax(&adj_idx[(size_t)s * NNODE + d], e);
        atomicAdd(&deg_src[s], 1);
        atomicAdd(&deg_dst[d], 1);
    }
}

// ---------------------------------------------------------------------------
// exclusive scan of both degree arrays (2048 each), single block
// ---------------------------------------------------------------------------
__global__ __launch_bounds__(256) void scan_kernel(const int* __restrict__ deg_src,
                                                   const int* __restrict__ deg_dst,
                                                   int* __restrict__ off_src,
                                                   int* __restrict__ off_dst,
                                                   int* __restrict__ cur_src,
                                                   int* __restrict__ cur_dst) {
    __shared__ int part[256];
    int t = threadIdx.x;
    for (int which = 0; which < 2; ++which) {
        const int* deg = which ? deg_dst : deg_src;
        int* off = which ? off_dst : off_src;
        int* cur = which ? cur_dst : cur_src;
        __syncthreads();
        int base = t * 8;
        int local[8];
        int s = 0;
        #pragma unroll
        for (int i = 0; i < 8; ++i) { local[i] = deg[base + i]; s += local[i]; }
        part[t] = s;
        __syncthreads();
        if (t == 0) {
            int run = 0;
            for (int i = 0; i < 256; ++i) { int v = part[i]; part[i] = run; run += v; }
        }
        __syncthreads();
        int run = part[t];
        #pragma unroll
        for (int i = 0; i < 8; ++i) {
            off[base + i] = run;
            cur[base + i] = run;
            run += local[i];
        }
        if (t == 255) off[NNODE] = run;
    }
}

// ---------------------------------------------------------------------------
// fill CSR edge lists (order within bucket arbitrary — sums only)
// ---------------------------------------------------------------------------
__global__ __launch_bounds__(256) void fill_kernel(const int* __restrict__ ei,
                                                   int* __restrict__ cur_src,
                                                   int* __restrict__ cur_dst,
                                                   int* __restrict__ list_src,
                                                   int* __restrict__ list_dst) {
    int e = blockIdx.x * 256 + threadIdx.x;
    if (e < NEDGE) {
        int s = ei[e];
        int d = ei[NEDGE + e];
        int p1 = atomicAdd(&cur_src[s], 1);
        list_src[p1] = e;
        int p2 = atomicAdd(&cur_dst[d], 1);
        list_dst[p2] = e;
    }
}

// ---------------------------------------------------------------------------
// sparse residuals: 16-lane group per edge (avg out-degree ~16; a full wave
// left 75% of lanes idle). lanes walk out-neighbors of A with dedup winner
// check, probe adj_idx[B][C]. Writes res and w = exp(-res).
// ---------------------------------------------------------------------------
__global__ __launch_bounds__(256) void residual_kernel(const int* __restrict__ ei,
                                                       const float* __restrict__ dist,
                                                       const int* __restrict__ adj_idx,
                                                       const int* __restrict__ off_src,
                                                       const int* __restrict__ list_src,
                                                       float* __restrict__ res_out,
                                                       float* __restrict__ wbuf) {
    int grp = threadIdx.x >> 4;        // 0..15
    int lane = threadIdx.x & 15;
    int e = blockIdx.x * 16 + grp;
    int A = ei[e];
    int C = ei[NEDGE + e];
    int beg = off_src[A];
    int end = off_src[A + 1];
    float sum = 0.0f, cnt = 0.0f;
    for (int i = beg + lane; i < end; i += 16) {
        int ep = list_src[i];
        int B = ei[NEDGE + ep];
        if (adj_idx[(size_t)A * NNODE + B] == ep) {      // ep is the winner of (A,B)
            int idx2 = adj_idx[(size_t)B * NNODE + C];
            if (idx2 >= 0) { sum += dist[ep] + dist[idx2]; cnt += 1.0f; }
        }
    }
    #pragma unroll
    for (int off = 8; off > 0; off >>= 1) {
        sum += __shfl_down(sum, off, 16);
        cnt += __shfl_down(cnt, off, 16);
    }
    if (lane == 0) {
        float d = dist[e];
        float mean = (cnt > 0.0f) ? (sum / cnt) : d;
        float r = fabsf(d - mean);
        res_out[e] = r;
        wbuf[e] = expf(-r);
    }
}

// ---------------------------------------------------------------------------
// message MLP v3: 32 edges/block, 256 threads, __launch_bounds__(256,4)
// (VGPR cap 128 — v2's acc[4][8] + full unroll spilled to scratch: VGPR=256,
//  1.4 GB spill traffic/dispatch, 660us. Keep acc[2][8], #pragma unroll 2.)
// eg = tid&15 -> 2 edges each; jg = tid>>4 -> 8 outputs each.
// Strides 35/131 (== 3 mod 32) keep x reads conflict-free; weight reads are
// 4-address b128 broadcasts. Writes RAW messages (no atomics).
// ---------------------------------------------------------------------------
__global__ __launch_bounds__(256, 4) void msg_kernel(const float* __restrict__ mu,
                                                  const float* __restrict__ sigma,
                                                  const int* __restrict__ ei,
                                                  const float* __restrict__ dist,
                                                  const float* __restrict__ conf,
                                                  const float* __restrict__ angle,
                                                  const float* __restrict__ ddiff,
                                                  const float* __restrict__ w1,
                                                  const float* __restrict__ b1,
                                                  const float* __restrict__ w2,
                                                  const float* __restrict__ b2,
                                                  float* __restrict__ wmsg) {
    __shared__ float xs[EB][35];       // 4.5 KB (35 % 32 == 3)
    __shared__ float wt[32 * HID];     // 16 KB
    __shared__ float hs[EB][131];      // 16.8 KB (131 % 32 == 3)
    __shared__ int   sid[EB];
    int tid = threadIdx.x;
    int e0 = blockIdx.x * EB;
    int eg = tid & 15;
    int jg = tid >> 4;
    int j0 = jg * 8;
    if (tid < EB) sid[tid] = ei[e0 + tid];
    __syncthreads();

    float acc[2][8];
    #pragma unroll
    for (int q = 0; q < 2; ++q)
        #pragma unroll
        for (int r = 0; r < 8; ++r) acc[q][r] = b1[j0 + r];

    // ---- layer 1: KIN = 260 = 8*32 + 4 ----
    for (int t = 0; t < 9; ++t) {
        int k0 = t * 32;
        int rows = (t == 8) ? 4 : 32;
        __syncthreads();
        // stage x tile: 32 edges x 32 floats, one float4 per thread
        if (t < 8) {
            const float* basep = (t < 4) ? mu : sigma;
            int kbase = (t < 4) ? k0 : (k0 - HID);
            int e = tid >> 3;          // 0..31
            int k4 = (tid & 7) * 4;    // 0..28
            const float* row = basep + (size_t)sid[e] * HID + kbase + k4;
            float4 v = *(const float4*)row;
            xs[e][k4] = v.x; xs[e][k4 + 1] = v.y;
            xs[e][k4 + 2] = v.z; xs[e][k4 + 3] = v.w;
        } else if (tid < EB) {
            int ge = e0 + tid;
            xs[tid][0] = dist[ge];
            xs[tid][1] = conf[ge];
            xs[tid][2] = angle[ge];
            xs[tid][3] = ddiff[ge];
        }
        // stage weight tile
        {
            const float4* src = (const float4*)(w1 + (size_t)k0 * HID);
            int n4 = rows * (HID / 4);
            for (int i = tid; i < n4; i += 256) ((float4*)wt)[i] = src[i];
        }
        __syncthreads();
        #pragma unroll 2
        for (int kk = 0; kk < rows; ++kk) {
            float4 wa = *(const float4*)&wt[kk * HID + j0];
            float4 wb = *(const float4*)&wt[kk * HID + j0 + 4];
            #pragma unroll
            for (int q = 0; q < 2; ++q) {
                float xv = xs[2 * eg + q][kk];
                acc[q][0] = fmaf(xv, wa.x, acc[q][0]);
                acc[q][1] = fmaf(xv, wa.y, acc[q][1]);
                acc[q][2] = fmaf(xv, wa.z, acc[q][2]);
                acc[q][3] = fmaf(xv, wa.w, acc[q][3]);
                acc[q][4] = fmaf(xv, wb.x, acc[q][4]);
                acc[q][5] = fmaf(xv, wb.y, acc[q][5]);
                acc[q][6] = fmaf(xv, wb.z, acc[q][6]);
                acc[q][7] = fmaf(xv, wb.w, acc[q][7]);
            }
        }
    }
    // relu -> hs
    #pragma unroll
    for (int q = 0; q < 2; ++q)
        #pragma unroll
        for (int r = 0; r < 8; ++r) hs[2 * eg + q][j0 + r] = fmaxf(acc[q][r], 0.0f);

    // ---- layer 2: 128 = 4*32 ----
    #pragma unroll
    for (int q = 0; q < 2; ++q)
        #pragma unroll
        for (int r = 0; r < 8; ++r) acc[q][r] = b2[j0 + r];
    for (int t = 0; t < 4; ++t) {
        int k0 = t * 32;
        __syncthreads();
        {
            const float4* src = (const float4*)(w2 + (size_t)k0 * HID);
            for (int i = tid; i < 32 * (HID / 4); i += 256) ((float4*)wt)[i] = src[i];
        }
        __syncthreads();
        #pragma unroll 2
        for (int kk = 0; kk < 32; ++kk) {
            float4 wa = *(const float4*)&wt[kk * HID + j0];
            float4 wb = *(const float4*)&wt[kk * HID + j0 + 4];
            #pragma unroll
            for (int q = 0; q < 2; ++q) {
                float xv = hs[2 * eg + q][k0 + kk];
                acc[q][0] = fmaf(xv, wa.x, acc[q][0]);
                acc[q][1] = fmaf(xv, wa.y, acc[q][1]);
                acc[q][2] = fmaf(xv, wa.z, acc[q][2]);
                acc[q][3] = fmaf(xv, wa.w, acc[q][3]);
                acc[q][4] = fmaf(xv, wb.x, acc[q][4]);
                acc[q][5] = fmaf(xv, wb.y, acc[q][5]);
                acc[q][6] = fmaf(xv, wb.z, acc[q][6]);
                acc[q][7] = fmaf(xv, wb.w, acc[q][7]);
            }
        }
    }
    // store raw messages
    #pragma unroll
    for (int q = 0; q < 2; ++q) {
        float* orow = wmsg + (size_t)(e0 + 2 * eg + q) * HID + j0;
        float4 v0 = make_float4(acc[q][0], acc[q][1], acc[q][2], acc[q][3]);
        float4 v1 = make_float4(acc[q][4], acc[q][5], acc[q][6], acc[q][7]);
        *(float4*)orow = v0;
        *(float4*)(orow + 4) = v1;
    }
}

// ---------------------------------------------------------------------------
// gather: per node, sum weighted incoming messages via dst-CSR (coalesced),
// normalize, and compute mean incoming residual. No atomics.
// ---------------------------------------------------------------------------
__global__ __launch_bounds__(128) void gather_kernel(const float* __restrict__ wmsg,
                                                     const float* __restrict__ wbuf,
                                                     const float* __restrict__ res,
                                                     const int* __restrict__ off_dst,
                                                     const int* __restrict__ list_dst,
                                                     float* __restrict__ aggn,
                                                     float* __restrict__ mean_r) {
    int n = blockIdx.x;
    int j = threadIdx.x;
    int beg = off_dst[n];
    int end = off_dst[n + 1];
    float acc = 0.0f, ws = 0.0f, rs = 0.0f;
    for (int i = beg; i < end; ++i) {
        int e = list_dst[i];
        float w = wbuf[e];
        acc += w * wmsg[(size_t)e * HID + j];
        ws += w;
        rs += res[e];
    }
    aggn[(size_t)n * HID + j] = acc / fmaxf(ws, 1e-8f);
    if (j == 0) {
        float c = (float)(end - beg);
        mean_r[n] = rs / fmaxf(c, 1.0f);
    }
}

// ---------------------------------------------------------------------------
// node mu MLP: mu_new = mu + mlp(aggn)
// ---------------------------------------------------------------------------
__global__ __launch_bounds__(256) void mu_kernel(const float* __restrict__ mu,
                                                 const float* __restrict__ aggn,
                                                 const float* __restrict__ w1,
                                                 const float* __restrict__ b1,
                                                 const float* __restrict__ w2,
                                                 const float* __restrict__ b2,
                                                 float* __restrict__ out) {
    __shared__ float xs[16][132];
    __shared__ float wt[32 * HID];
    __shared__ float hs[16][132];
    int tid = threadIdx.x;
    int n0 = blockIdx.x * 16;
    {
        int nl = tid >> 4, l = tid & 15;
        int n = n0 + nl;
        for (int k = l; k < HID; k += 16)
            xs[nl][k] = aggn[(size_t)n * HID + k];
    }
    __syncthreads();
    int nl = tid >> 4, jg = tid & 15, j0 = jg * 8;
    float acc[8];
    #pragma unroll
    for (int r = 0; r < 8; ++r) acc[r] = b1[j0 + r];
    for (int k0 = 0; k0 < HID; k0 += 32) {
        __syncthreads();
        for (int i = tid; i < 32 * (HID / 4); i += 256)
            ((float4*)wt)[i] = ((const float4*)(w1 + (size_t)k0 * HID))[i];
        __syncthreads();
        #pragma unroll 2
        for (int kk = 0; kk < 32; ++kk) {
            float xv = xs[nl][k0 + kk];
            const float* wr = wt + kk * HID + j0;
            #pragma unroll
            for (int r = 0; r < 8; ++r) acc[r] = fmaf(xv, wr[r], acc[r]);
        }
    }
    #pragma unroll
    for (int r = 0; r < 8; ++r) hs[nl][j0 + r] = fmaxf(acc[r], 0.0f);
    #pragma unroll
    for (int r = 0; r < 8; ++r) acc[r] = b2[j0 + r];
    for (int k0 = 0; k0 < HID; k0 += 32) {
        __syncthreads();
        for (int i = tid; i < 32 * (HID / 4); i += 256)
            ((float4*)wt)[i] = ((const float4*)(w2 + (size_t)k0 * HID))[i];
        __syncthreads();
        #pragma unroll 2
        for (int kk = 0; kk < 32; ++kk) {
            float xv = hs[nl][k0 + kk];
            const float* wr = wt + kk * HID + j0;
            #pragma unroll
            for (int r = 0; r < 8; ++r) acc[r] = fmaf(xv, wr[r], acc[r]);
        }
    }
    int n = n0 + nl;
    #pragma unroll
    for (int r = 0; r < 8; ++r)
        out[(size_t)n * HID + j0 + r] = mu[(size_t)n * HID + j0 + r] + acc[r];
}

// ---------------------------------------------------------------------------
// node sigma MLP: sigma_new = softplus(mlp([aggn, mean_r]))  (K = 129)
// ---------------------------------------------------------------------------
__global__ __launch_bounds__(256) void sig_kernel(const float* __restrict__ aggn,
                                                  const float* __restrict__ mean_r,
                                                  const float* __restrict__ w1,
                                                  const float* __restrict__ b1,
                                                  const float* __restrict__ w2,
                                                  const float* __restrict__ b2,
                                                  float* __restrict__ out) {
    __shared__ float xs[16][132];
    __shared__ float wt[32 * HID];
    __shared__ float hs[16][132];
    int tid = threadIdx.x;
    int n0 = blockIdx.x * 16;
    {
        int nl = tid >> 4, l = tid & 15;
        int n = n0 + nl;
        for (int k = l; k < HID; k += 16)
            xs[nl][k] = aggn[(size_t)n * HID + k];
        if (l == 0)
            xs[nl][HID] = mean_r[n];
    }
    __syncthreads();
    int nl = tid >> 4, jg = tid & 15, j0 = jg * 8;
    float acc[8];
    #pragma unroll
    for (int r = 0; r < 8; ++r) acc[r] = b1[j0 + r];
    for (int k0 = 0; k0 < 129; k0 += 32) {
        int rows = (129 - k0 < 32) ? (129 - k0) : 32;
        __syncthreads();
        for (int i = tid; i < rows * (HID / 4); i += 256)
            ((float4*)wt)[i] = ((const float4*)(w1 + (size_t)k0 * HID))[i];
        __syncthreads();
        #pragma unroll 2
        for (int kk = 0; kk < rows; ++kk) {
            float xv = xs[nl][k0 + kk];
            const float* wr = wt + kk * HID + j0;
            #pragma unroll
            for (int r = 0; r < 8; ++r) acc[r] = fmaf(xv, wr[r], acc[r]);
        }
    }
    #pragma unroll
    for (int r = 0; r < 8; ++r) hs[nl][j0 + r] = fmaxf(acc[r], 0.0f);
    #pragma unroll
    for (int r = 0; r < 8; ++r) acc[r] = b2[j0 + r];
    for (int k0 = 0; k0 < HID; k0 += 32) {
        __syncthreads();
        for (int i = tid; i < 32 * (HID / 4); i += 256)
            ((float4*)wt)[i] = ((const float4*)(w2 + (size_t)k0 * HID))[i];
        __syncthreads();
        #pragma unroll 2
        for (int kk = 0; kk < 32; ++kk) {
            float xv = hs[nl][k0 + kk];
            const float* wr = wt + kk * HID + j0;
            #pragma unroll
            for (int r = 0; r < 8; ++r) acc[r] = fmaf(xv, wr[r], acc[r]);
        }
    }
    int n = n0 + nl;
    #pragma unroll
    for (int r = 0; r < 8; ++r) {
        float x = acc[r];
        out[(size_t)n * HID + j0 + r] = fmaxf(x, 0.0f) + log1pf(expf(-fabsf(x)));
    }
}

// ---------------------------------------------------------------------------
extern "C" void kernel_launch(void* const* d_in, const int* in_sizes, int n_in,
                              void* d_out, int out_size, void* d_ws, size_t ws_size,
                              hipStream_t stream) {
    const float* mu     = (const float*)d_in[0];
    const float* sigma  = (const float*)d_in[1];
    const int*   ei     = (const int*)d_in[2];
    const float* dist   = (const float*)d_in[3];
    const float* conf   = (const float*)d_in[4];
    const float* angle  = (const float*)d_in[5];
    const float* ddiff  = (const float*)d_in[6];
    const float* msg_w1 = (const float*)d_in[7];
    const float* msg_b1 = (const float*)d_in[8];
    const float* msg_w2 = (const float*)d_in[9];
    const float* msg_b2 = (const float*)d_in[10];
    const float* mu_w1  = (const float*)d_in[11];
    const float* mu_b1  = (const float*)d_in[12];
    const float* mu_w2  = (const float*)d_in[13];
    const float* mu_b2  = (const float*)d_in[14];
    const float* sig_w1 = (const float*)d_in[15];
    const float* sig_b1 = (const float*)d_in[16];
    const float* sig_w2 = (const float*)d_in[17];
    const float* sig_b2 = (const float*)d_in[18];

    float* out_mu  = (float*)d_out;
    float* out_sig = out_mu + (size_t)NNODE * HID;
    float* out_res = out_sig + (size_t)NNODE * HID;

    char* ws = (char*)d_ws;
    size_t o = 0;
    int*   adj_idx  = (int*)(ws + o);   o += (size_t)NMAT * 4;           // 16.78 MB
    float* wmsg     = (float*)(ws + o); o += (size_t)NEDGE * HID * 4;    // 16.78 MB
    float* wbuf     = (float*)(ws + o); o += (size_t)NEDGE * 4;
    float* aggn     = (float*)(ws + o); o += (size_t)NNODE * HID * 4;
    float* mean_r   = (float*)(ws + o); o += (size_t)NNODE * 4;
    int*   deg_src  = (int*)(ws + o);   o += (size_t)NNODE * 4;
    int*   deg_dst  = (int*)(ws + o);   o += (size_t)NNODE * 4;
    int*   off_src  = (int*)(ws + o);   o += (size_t)(NNODE + 1) * 4;
    int*   off_dst  = (int*)(ws + o);   o += (size_t)(NNODE + 1) * 4;
    int*   cur_src  = (int*)(ws + o);   o += (size_t)NNODE * 4;
    int*   cur_dst  = (int*)(ws + o);   o += (size_t)NNODE * 4;
    int*   list_src = (int*)(ws + o);   o += (size_t)NEDGE * 4;
    int*   list_dst = (int*)(ws + o);   o += (size_t)NEDGE * 4;

    hipLaunchKernelGGL(init_kernel, dim3(4096), dim3(256), 0, stream,
                       adj_idx, deg_src, deg_dst);
    hipLaunchKernelGGL(scatter_kernel, dim3(NEDGE / 256), dim3(256), 0, stream,
                       ei, adj_idx, deg_src, deg_dst);
    hipLaunchKernelGGL(scan_kernel, dim3(1), dim3(256), 0, stream,
                       deg_src, deg_dst, off_src, off_dst, cur_src, cur_dst);
    hipLaunchKernelGGL(fill_kernel, dim3(NEDGE / 256), dim3(256), 0, stream,
                       ei, cur_src, cur_dst, list_src, list_dst);
    hipLaunchKernelGGL(residual_kernel, dim3(NEDGE / 16), dim3(256), 0, stream,
                       ei, dist, adj_idx, off_src, list_src, out_res, wbuf);
    hipLaunchKernelGGL(msg_kernel, dim3(NEDGE / EB), dim3(256), 0, stream,
                       mu, sigma, ei, dist, conf, angle, ddiff,
                       msg_w1, msg_b1, msg_w2, msg_b2, wmsg);
    hipLaunchKernelGGL(gather_kernel, dim3(NNODE), dim3(128), 0, stream,
                       wmsg, wbuf, out_res, off_dst, list_dst, aggn, mean_r);
    hipLaunchKernelGGL(mu_kernel, dim3(NNODE / 16), dim3(256), 0, stream,
                       mu, aggn, mu_w1, mu_b1, mu_w2, mu_b2, out_mu);
    hipLaunchKernelGGL(sig_kernel, dim3(NNODE / 16), dim3(256), 0, stream,
                       aggn, mean_r, sig_w1, sig_b1, sig_w2, sig_b2, out_sig);
}

// Round 7
// 216.223 us; speedup vs baseline: 3.9403x; 1.1175x over previous
//
#include <hip/hip_runtime.h>
#include <math.h>

#define NNODE 2048
#define NEDGE 32768
#define HID   128
#define NMAT  (NNODE * NNODE)
#define EB    64           // edges per block in msg kernel

// ---------------------------------------------------------------------------
// init: adj_idx = -1 (int4 stores, exactly 1 per thread), degree hists = 0
// ---------------------------------------------------------------------------
__global__ __launch_bounds__(256) void init_kernel(int4* __restrict__ adj4,
                                                   int* __restrict__ deg_src,
                                                   int* __restrict__ deg_dst) {
    int gid = blockIdx.x * 256 + threadIdx.x;   // 4096 blocks -> 1,048,576 = NMAT/4
    adj4[gid] = make_int4(-1, -1, -1, -1);
    if (gid < NNODE) { deg_src[gid] = 0; deg_dst[gid] = 0; }
}

// ---------------------------------------------------------------------------
// scatter+hist: last-edge-index-wins dedup matrix + degree histograms
// ---------------------------------------------------------------------------
__global__ __launch_bounds__(256) void scatter_kernel(const int* __restrict__ ei,
                                                      int* __restrict__ adj_idx,
                                                      int* __restrict__ deg_src,
                                                      int* __restrict__ deg_dst) {
    int e = blockIdx.x * 256 + threadIdx.x;
    if (e < NEDGE) {
        int s = ei[e];
        int d = ei[NEDGE + e];
        atomicMax(&adj_idx[(size_t)s * NNODE + d], e);
        atomicAdd(&deg_src[s], 1);
        atomicAdd(&deg_dst[d], 1);
    }
}

// ---------------------------------------------------------------------------
// exclusive scan of both degree arrays (2048 each), single block
// ---------------------------------------------------------------------------
__global__ __launch_bounds__(256) void scan_kernel(const int* __restrict__ deg_src,
                                                   const int* __restrict__ deg_dst,
                                                   int* __restrict__ off_src,
                                                   int* __restrict__ off_dst,
                                                   int* __restrict__ cur_src,
                                                   int* __restrict__ cur_dst) {
    __shared__ int part[256];
    int t = threadIdx.x;
    for (int which = 0; which < 2; ++which) {
        const int* deg = which ? deg_dst : deg_src;
        int* off = which ? off_dst : off_src;
        int* cur = which ? cur_dst : cur_src;
        __syncthreads();
        int base = t * 8;
        int local[8];
        int s = 0;
        #pragma unroll
        for (int i = 0; i < 8; ++i) { local[i] = deg[base + i]; s += local[i]; }
        part[t] = s;
        __syncthreads();
        if (t == 0) {
            int run = 0;
            for (int i = 0; i < 256; ++i) { int v = part[i]; part[i] = run; run += v; }
        }
        __syncthreads();
        int run = part[t];
        #pragma unroll
        for (int i = 0; i < 8; ++i) {
            off[base + i] = run;
            cur[base + i] = run;
            run += local[i];
        }
        if (t == 255) off[NNODE] = run;
    }
}

// ---------------------------------------------------------------------------
// fill CSR edge lists (order within bucket arbitrary — sums only)
// ---------------------------------------------------------------------------
__global__ __launch_bounds__(256) void fill_kernel(const int* __restrict__ ei,
                                                   int* __restrict__ cur_src,
                                                   int* __restrict__ cur_dst,
                                                   int* __restrict__ list_src,
                                                   int* __restrict__ list_dst) {
    int e = blockIdx.x * 256 + threadIdx.x;
    if (e < NEDGE) {
        int s = ei[e];
        int d = ei[NEDGE + e];
        int p1 = atomicAdd(&cur_src[s], 1);
        list_src[p1] = e;
        int p2 = atomicAdd(&cur_dst[d], 1);
        list_dst[p2] = e;
    }
}

// ---------------------------------------------------------------------------
// sparse residuals: 16-lane group per edge (avg out-degree ~16). lanes walk
// out-neighbors of A with dedup winner check, probe adj_idx[B][C].
// Writes res and w = exp(-res).
// ---------------------------------------------------------------------------
__global__ __launch_bounds__(256) void residual_kernel(const int* __restrict__ ei,
                                                       const float* __restrict__ dist,
                                                       const int* __restrict__ adj_idx,
                                                       const int* __restrict__ off_src,
                                                       const int* __restrict__ list_src,
                                                       float* __restrict__ res_out,
                                                       float* __restrict__ wbuf) {
    int grp = threadIdx.x >> 4;        // 0..15
    int lane = threadIdx.x & 15;
    int e = blockIdx.x * 16 + grp;
    int A = ei[e];
    int C = ei[NEDGE + e];
    int beg = off_src[A];
    int end = off_src[A + 1];
    float sum = 0.0f, cnt = 0.0f;
    for (int i = beg + lane; i < end; i += 16) {
        int ep = list_src[i];
        int B = ei[NEDGE + ep];
        if (adj_idx[(size_t)A * NNODE + B] == ep) {      // ep is the winner of (A,B)
            int idx2 = adj_idx[(size_t)B * NNODE + C];
            if (idx2 >= 0) { sum += dist[ep] + dist[idx2]; cnt += 1.0f; }
        }
    }
    #pragma unroll
    for (int off = 8; off > 0; off >>= 1) {
        sum += __shfl_down(sum, off, 16);
        cnt += __shfl_down(cnt, off, 16);
    }
    if (lane == 0) {
        float d = dist[e];
        float mean = (cnt > 0.0f) ? (sum / cnt) : d;
        float r = fabsf(d - mean);
        res_out[e] = r;
        wbuf[e] = expf(-r);
    }
}

// ---------------------------------------------------------------------------
// node_part: np[n] = mu[n] @ W1[0:128] + sigma[n] @ W1[128:256] + b1
// (layer-1 of the msg MLP depends only on the node -> 16x FLOP cut vs per-edge)
// nl = tid&15 (node), jg = tid>>4 (8-output group): per-wave jg is 4-valued
// -> wt b128 reads conflict-free; xs stride 35 -> nl reads 1 bank apart.
// ---------------------------------------------------------------------------
__global__ __launch_bounds__(256) void node_part_kernel(const float* __restrict__ mu,
                                                        const float* __restrict__ sigma,
                                                        const float* __restrict__ w1,
                                                        const float* __restrict__ b1,
                                                        float* __restrict__ np) {
    __shared__ float xs[16][35];
    __shared__ float wt[32 * HID];
    int tid = threadIdx.x;
    int n0 = blockIdx.x * 16;
    int nl = tid & 15, jg = tid >> 4, j0 = jg * 8;
    float acc[8];
    #pragma unroll
    for (int r = 0; r < 8; ++r) acc[r] = b1[j0 + r];
    for (int t = 0; t < 8; ++t) {
        const float* src = (t < 4) ? mu : sigma;
        int kbase = (t < 4) ? t * 32 : (t - 4) * 32;
        __syncthreads();
        if (tid < 128) {
            int row = tid >> 3, c4 = (tid & 7) << 2;
            float4 v = *(const float4*)(src + (size_t)(n0 + row) * HID + kbase + c4);
            xs[row][c4] = v.x; xs[row][c4 + 1] = v.y;
            xs[row][c4 + 2] = v.z; xs[row][c4 + 3] = v.w;
        }
        {
            const float4* wsrc = (const float4*)(w1 + (size_t)(t * 32) * HID);
            for (int i = tid; i < 32 * (HID / 4); i += 256) ((float4*)wt)[i] = wsrc[i];
        }
        __syncthreads();
        #pragma unroll 2
        for (int kk = 0; kk < 32; ++kk) {
            float xv = xs[nl][kk];
            const float* wr = wt + kk * HID + j0;
            #pragma unroll
            for (int r = 0; r < 8; ++r) acc[r] = fmaf(xv, wr[r], acc[r]);
        }
    }
    float* orow = np + (size_t)(n0 + nl) * HID + j0;
    *(float4*)orow = make_float4(acc[0], acc[1], acc[2], acc[3]);
    *(float4*)(orow + 4) = make_float4(acc[4], acc[5], acc[6], acc[7]);
}

// ---------------------------------------------------------------------------
// msg v4: h = relu(np[src] + ef @ W1c); msg = h @ W2 + b2. Layer-2 only GEMM
// (1.07 GF vs 3.26). 64 edges/block, acc[4][8]: 2 b128 + 4 b32 LDS reads per
// 32 FMA. VGPR capped by __launch_bounds__(256,4) + unroll 2 (v2 lesson).
// ---------------------------------------------------------------------------
__global__ __launch_bounds__(256, 4) void msg_kernel(const float* __restrict__ np,
                                                     const int* __restrict__ ei,
                                                     const float* __restrict__ dist,
                                                     const float* __restrict__ conf,
                                                     const float* __restrict__ angle,
                                                     const float* __restrict__ ddiff,
                                                     const float* __restrict__ w1,
                                                     const float* __restrict__ w2,
                                                     const float* __restrict__ b2,
                                                     float* __restrict__ wmsg) {
    __shared__ float hs[EB][131];      // 33.5 KB (131 % 32 == 3 -> 2-way max)
    __shared__ float wt[32 * HID];     // 16 KB
    __shared__ float w1c[4][HID];      // 2 KB   (ef rows 256..259 of w1)
    __shared__ int   sid[EB];
    __shared__ float sef[4][EB];       // stride EB: 2-way max on reads
    int tid = threadIdx.x;
    int e0 = blockIdx.x * EB;
    if (tid < EB) {
        int ge = e0 + tid;
        sid[tid] = ei[ge];
        sef[0][tid] = dist[ge];
        sef[1][tid] = conf[ge];
        sef[2][tid] = angle[ge];
        sef[3][tid] = ddiff[ge];
    }
    for (int i = tid; i < 4 * HID; i += 256)
        w1c[i >> 7][i & 127] = w1[(size_t)(2 * HID) * HID + i];
    __syncthreads();

    int eg = tid & 15, jg = tid >> 4, j0 = jg * 8;

    // ---- h phase: gather np row, add ef@W1c, relu -> hs ----
    #pragma unroll
    for (int q = 0; q < 4; ++q) {
        int el = 4 * eg + q;
        const float* nrow = np + (size_t)sid[el] * HID + j0;
        float4 a = *(const float4*)nrow;
        float4 b = *(const float4*)(nrow + 4);
        float f0 = sef[0][el], f1 = sef[1][el], f2 = sef[2][el], f3 = sef[3][el];
        float base[8] = {a.x, a.y, a.z, a.w, b.x, b.y, b.z, b.w};
        #pragma unroll
        for (int r = 0; r < 8; ++r) {
            float v = base[r];
            v = fmaf(f0, w1c[0][j0 + r], v);
            v = fmaf(f1, w1c[1][j0 + r], v);
            v = fmaf(f2, w1c[2][j0 + r], v);
            v = fmaf(f3, w1c[3][j0 + r], v);
            hs[el][j0 + r] = fmaxf(v, 0.0f);
        }
    }

    // ---- layer 2: 128 = 4*32 ----
    float acc[4][8];
    #pragma unroll
    for (int q = 0; q < 4; ++q)
        #pragma unroll
        for (int r = 0; r < 8; ++r) acc[q][r] = b2[j0 + r];
    for (int t = 0; t < 4; ++t) {
        int k0 = t * 32;
        __syncthreads();   // t=0: also covers hs writes
        {
            const float4* src = (const float4*)(w2 + (size_t)k0 * HID);
            for (int i = tid; i < 32 * (HID / 4); i += 256) ((float4*)wt)[i] = src[i];
        }
        __syncthreads();
        #pragma unroll 2
        for (int kk = 0; kk < 32; ++kk) {
            float4 wa = *(const float4*)&wt[kk * HID + j0];
            float4 wb = *(const float4*)&wt[kk * HID + j0 + 4];
            #pragma unroll
            for (int q = 0; q < 4; ++q) {
                float xv = hs[4 * eg + q][k0 + kk];
                acc[q][0] = fmaf(xv, wa.x, acc[q][0]);
                acc[q][1] = fmaf(xv, wa.y, acc[q][1]);
                acc[q][2] = fmaf(xv, wa.z, acc[q][2]);
                acc[q][3] = fmaf(xv, wa.w, acc[q][3]);
                acc[q][4] = fmaf(xv, wb.x, acc[q][4]);
                acc[q][5] = fmaf(xv, wb.y, acc[q][5]);
                acc[q][6] = fmaf(xv, wb.z, acc[q][6]);
                acc[q][7] = fmaf(xv, wb.w, acc[q][7]);
            }
        }
    }
    #pragma unroll
    for (int q = 0; q < 4; ++q) {
        float* orow = wmsg + (size_t)(e0 + 4 * eg + q) * HID + j0;
        *(float4*)orow = make_float4(acc[q][0], acc[q][1], acc[q][2], acc[q][3]);
        *(float4*)(orow + 4) = make_float4(acc[q][4], acc[q][5], acc[q][6], acc[q][7]);
    }
}

// ---------------------------------------------------------------------------
// gather: per node, sum weighted incoming messages via dst-CSR (coalesced),
// normalize, and compute mean incoming residual. No atomics.
// ---------------------------------------------------------------------------
__global__ __launch_bounds__(128) void gather_kernel(const float* __restrict__ wmsg,
                                                     const float* __restrict__ wbuf,
                                                     const float* __restrict__ res,
                                                     const int* __restrict__ off_dst,
                                                     const int* __restrict__ list_dst,
                                                     float* __restrict__ aggn,
                                                     float* __restrict__ mean_r) {
    int n = blockIdx.x;
    int j = threadIdx.x;
    int beg = off_dst[n];
    int end = off_dst[n + 1];
    float acc = 0.0f, ws = 0.0f, rs = 0.0f;
    for (int i = beg; i < end; ++i) {
        int e = list_dst[i];
        float w = wbuf[e];
        acc += w * wmsg[(size_t)e * HID + j];
        ws += w;
        rs += res[e];
    }
    aggn[(size_t)n * HID + j] = acc / fmaxf(ws, 1e-8f);
    if (j == 0) {
        float c = (float)(end - beg);
        mean_r[n] = rs / fmaxf(c, 1.0f);
    }
}

// ---------------------------------------------------------------------------
// node_out: merged mu + sigma MLPs (256 blocks: first 128 mu, rest sigma).
// mu: out = mu + mlp(aggn); sig: out = softplus(mlp([aggn, mean_r])), K1=129.
// nl = tid&15, jg = tid>>4 (wt reads conflict-free as in node_part).
// ---------------------------------------------------------------------------
__global__ __launch_bounds__(256) void node_out_kernel(const float* __restrict__ mu,
                                                       const float* __restrict__ aggn,
                                                       const float* __restrict__ mean_r,
                                                       const float* __restrict__ mu_w1,
                                                       const float* __restrict__ mu_b1,
                                                       const float* __restrict__ mu_w2,
                                                       const float* __restrict__ mu_b2,
                                                       const float* __restrict__ sg_w1,
                                                       const float* __restrict__ sg_b1,
                                                       const float* __restrict__ sg_w2,
                                                       const float* __restrict__ sg_b2,
                                                       float* __restrict__ out_mu,
                                                       float* __restrict__ out_sig) {
    __shared__ float xs[16][133];   // 129 cols max; stride 133 (5 mod 32)
    __shared__ float wt[32 * HID];
    __shared__ float hs[16][131];
    bool is_mu = blockIdx.x < (NNODE / 16);
    int bi = is_mu ? blockIdx.x : blockIdx.x - NNODE / 16;
    int n0 = bi * 16;
    const float* w1 = is_mu ? mu_w1 : sg_w1;
    const float* b1 = is_mu ? mu_b1 : sg_b1;
    const float* w2 = is_mu ? mu_w2 : sg_w2;
    const float* b2 = is_mu ? mu_b2 : sg_b2;
    int K1 = is_mu ? HID : (HID + 1);
    int tid = threadIdx.x;
    int nl = tid & 15, jg = tid >> 4, j0 = jg * 8;
    // stage input rows
    for (int i = tid; i < 512; i += 256) {
        int row = i >> 5, c4 = (i & 31) * 4;
        float4 v = *(const float4*)(aggn + (size_t)(n0 + row) * HID + c4);
        xs[row][c4] = v.x; xs[row][c4 + 1] = v.y;
        xs[row][c4 + 2] = v.z; xs[row][c4 + 3] = v.w;
    }
    if (!is_mu && tid < 16) xs[tid][HID] = mean_r[n0 + tid];
    float acc[8];
    #pragma unroll
    for (int r = 0; r < 8; ++r) acc[r] = b1[j0 + r];
    for (int k0 = 0; k0 < K1; k0 += 32) {
        int rows = (K1 - k0 < 32) ? (K1 - k0) : 32;
        __syncthreads();
        {
            const float4* src = (const float4*)(w1 + (size_t)k0 * HID);
            for (int i = tid; i < rows * (HID / 4); i += 256) ((float4*)wt)[i] = src[i];
        }
        __syncthreads();
        #pragma unroll 2
        for (int kk = 0; kk < rows; ++kk) {
            float xv = xs[nl][k0 + kk];
            const float* wr = wt + kk * HID + j0;
            #pragma unroll
            for (int r = 0; r < 8; ++r) acc[r] = fmaf(xv, wr[r], acc[r]);
        }
    }
    #pragma unroll
    for (int r = 0; r < 8; ++r) hs[nl][j0 + r] = fmaxf(acc[r], 0.0f);
    #pragma unroll
    for (int r = 0; r < 8; ++r) acc[r] = b2[j0 + r];
    for (int k0 = 0; k0 < HID; k0 += 32) {
        __syncthreads();
        {
            const float4* src = (const float4*)(w2 + (size_t)k0 * HID);
            for (int i = tid; i < 32 * (HID / 4); i += 256) ((float4*)wt)[i] = src[i];
        }
        __syncthreads();
        #pragma unroll 2
        for (int kk = 0; kk < 32; ++kk) {
            float xv = hs[nl][k0 + kk];
            const float* wr = wt + kk * HID + j0;
            #pragma unroll
            for (int r = 0; r < 8; ++r) acc[r] = fmaf(xv, wr[r], acc[r]);
        }
    }
    int n = n0 + nl;
    if (is_mu) {
        #pragma unroll
        for (int r = 0; r < 8; ++r)
            out_mu[(size_t)n * HID + j0 + r] = mu[(size_t)n * HID + j0 + r] + acc[r];
    } else {
        #pragma unroll
        for (int r = 0; r < 8; ++r) {
            float x = acc[r];
            out_sig[(size_t)n * HID + j0 + r] = fmaxf(x, 0.0f) + log1pf(expf(-fabsf(x)));
        }
    }
}

// ---------------------------------------------------------------------------
extern "C" void kernel_launch(void* const* d_in, const int* in_sizes, int n_in,
                              void* d_out, int out_size, void* d_ws, size_t ws_size,
                              hipStream_t stream) {
    const float* mu     = (const float*)d_in[0];
    const float* sigma  = (const float*)d_in[1];
    const int*   ei     = (const int*)d_in[2];
    const float* dist   = (const float*)d_in[3];
    const float* conf   = (const float*)d_in[4];
    const float* angle  = (const float*)d_in[5];
    const float* ddiff  = (const float*)d_in[6];
    const float* msg_w1 = (const float*)d_in[7];
    const float* msg_b1 = (const float*)d_in[8];
    const float* msg_w2 = (const float*)d_in[9];
    const float* msg_b2 = (const float*)d_in[10];
    const float* mu_w1  = (const float*)d_in[11];
    const float* mu_b1  = (const float*)d_in[12];
    const float* mu_w2  = (const float*)d_in[13];
    const float* mu_b2  = (const float*)d_in[14];
    const float* sig_w1 = (const float*)d_in[15];
    const float* sig_b1 = (const float*)d_in[16];
    const float* sig_w2 = (const float*)d_in[17];
    const float* sig_b2 = (const float*)d_in[18];

    float* out_mu  = (float*)d_out;
    float* out_sig = out_mu + (size_t)NNODE * HID;
    float* out_res = out_sig + (size_t)NNODE * HID;

    char* ws = (char*)d_ws;
    size_t o = 0;
    int*   adj_idx  = (int*)(ws + o);   o += (size_t)NMAT * 4;           // 16.78 MB
    float* wmsg     = (float*)(ws + o); o += (size_t)NEDGE * HID * 4;    // 16.78 MB
    float* wbuf     = (float*)(ws + o); o += (size_t)NEDGE * 4;
    float* aggn     = (float*)(ws + o); o += (size_t)NNODE * HID * 4;    // doubles as np
    float* mean_r   = (float*)(ws + o); o += (size_t)NNODE * 4;
    int*   deg_src  = (int*)(ws + o);   o += (size_t)NNODE * 4;
    int*   deg_dst  = (int*)(ws + o);   o += (size_t)NNODE * 4;
    int*   off_src  = (int*)(ws + o);   o += (size_t)(NNODE + 1) * 4;
    int*   off_dst  = (int*)(ws + o);   o += (size_t)(NNODE + 1) * 4;
    int*   cur_src  = (int*)(ws + o);   o += (size_t)NNODE * 4;
    int*   cur_dst  = (int*)(ws + o);   o += (size_t)NNODE * 4;
    int*   list_src = (int*)(ws + o);   o += (size_t)NEDGE * 4;
    int*   list_dst = (int*)(ws + o);   o += (size_t)NEDGE * 4;
    float* np = aggn;   // np dead before gather writes aggn -> safe alias

    hipLaunchKernelGGL(init_kernel, dim3(4096), dim3(256), 0, stream,
                       (int4*)adj_idx, deg_src, deg_dst);
    hipLaunchKernelGGL(scatter_kernel, dim3(NEDGE / 256), dim3(256), 0, stream,
                       ei, adj_idx, deg_src, deg_dst);
    hipLaunchKernelGGL(scan_kernel, dim3(1), dim3(256), 0, stream,
                       deg_src, deg_dst, off_src, off_dst, cur_src, cur_dst);
    hipLaunchKernelGGL(fill_kernel, dim3(NEDGE / 256), dim3(256), 0, stream,
                       ei, cur_src, cur_dst, list_src, list_dst);
    hipLaunchKernelGGL(residual_kernel, dim3(NEDGE / 16), dim3(256), 0, stream,
                       ei, dist, adj_idx, off_src, list_src, out_res, wbuf);
    hipLaunchKernelGGL(node_part_kernel, dim3(NNODE / 16), dim3(256), 0, stream,
                       mu, sigma, msg_w1, msg_b1, np);
    hipLaunchKernelGGL(msg_kernel, dim3(NEDGE / EB), dim3(256), 0, stream,
                       np, ei, dist, conf, angle, ddiff,
                       msg_w1, msg_w2, msg_b2, wmsg);
    hipLaunchKernelGGL(gather_kernel, dim3(NNODE), dim3(128), 0, stream,
                       wmsg, wbuf, out_res, off_dst, list_dst, aggn, mean_r);
    hipLaunchKernelGGL(node_out_kernel, dim3(2 * (NNODE / 16)), dim3(256), 0, stream,
                       mu, aggn, mean_r,
                       mu_w1, mu_b1, mu_w2, mu_b2,
                       sig_w1, sig_b1, sig_w2, sig_b2,
                       out_mu, out_sig);
}